// Round 9
// baseline (256.273 us; speedup 1.0000x reference)
//
#include <hip/hip_runtime.h>
#include <hip/hip_bf16.h>

typedef __bf16 bf16x8 __attribute__((ext_vector_type(8)));
typedef float f32x4 __attribute__((ext_vector_type(4)));
typedef float f32x16 __attribute__((ext_vector_type(16)));
typedef int int4v __attribute__((ext_vector_type(4)));

#define NB 4
#define NC 256
#define NN 4096
#define BK 32
#define NT_W 32   // tiles per wave: 4-way j-split, 32 tiles * 32 j = 1024 j each

__device__ __forceinline__ void stage16(const void* g, void* l) {
    __builtin_amdgcn_global_load_lds(
        (const __attribute__((address_space(1))) unsigned int*)g,
        (__attribute__((address_space(3))) unsigned int*)l, 16, 0, 0);
}
__device__ __forceinline__ int cvtpk(float lo, float hi) {
    int d;
    asm("v_cvt_pk_bf16_f32 %0, %1, %2" : "=v"(d) : "v"(lo), "v"(hi));
    return d;
}
// a.hi-lanes <-> b.lo-lanes (v_permlane32_swap_b32: vdst[32:63] <-> vsrc[0:31])
__device__ __forceinline__ void plswap(int& a, int& b) {
    asm("v_permlane32_swap_b32 %0, %1" : "+v"(a), "+v"(b));
}

// ---------- prep: x fp32 [b][c][n] -> xt bf16 [b][n][c] (transposed),
//                                      xv bf16 [b][tile(128)][c(256)][j(32)] (tile-major V^T) ----------
__global__ __launch_bounds__(256) void prep_kernel(const float* __restrict__ x,
                                                   __bf16* __restrict__ xt,
                                                   __bf16* __restrict__ xv) {
    __shared__ __align__(16) __bf16 tile[64 * 64];  // swizzled 16B chunks, no pad
    const int b = blockIdx.z, c0 = blockIdx.y * 64, n0 = blockIdx.x * 64;
    const int t = threadIdx.x;
    {
        const int cc = t >> 2, nch = (t & 3) << 4;   // 16 floats per thread
        const float* src = x + ((size_t)(b * NC + c0 + cc)) * NN + n0 + nch;
        f32x4 v[4];
        v[0] = *(const f32x4*)(src);
        v[1] = *(const f32x4*)(src + 4);
        v[2] = *(const f32x4*)(src + 8);
        v[3] = *(const f32x4*)(src + 12);
        bf16x8 o[2];
#pragma unroll
        for (int q = 0; q < 2; ++q)
#pragma unroll
            for (int k = 0; k < 8; ++k)
                o[q][k] = (__bf16)v[q * 2 + (k >> 2)][k & 3];
        // V^T tile-major write: tile = (n0+nch)/32, row c, j-offset = nch&31
        const int tile_idx = (n0 + nch) >> 5;
        const int off_j = nch & 31;                  // 0 or 16
        __bf16* dstv = xv + (((size_t)(b * (NN / 32) + tile_idx)) * NC + (c0 + cc)) * 32 + off_j;
        *(bf16x8*)(dstv) = o[0];
        *(bf16x8*)(dstv + 8) = o[1];
        const int key = (cc ^ (cc >> 3)) & 7;        // rows 16 apart get distinct keys
#pragma unroll
        for (int q = 0; q < 2; ++q) {
            int nc = (nch >> 3) + q;
            *(bf16x8*)(&tile[cc * 64 + ((nc ^ key) << 3)]) = o[q];
        }
    }
    __syncthreads();
    {
        const int nn = t >> 2, cch = (t & 3) << 4;
        bf16x8 o[2];
#pragma unroll
        for (int k = 0; k < 16; ++k) {
            int r = cch + k;
            int key = (r ^ (r >> 3)) & 7;
            o[k >> 3][k & 7] = tile[r * 64 + (((nn >> 3) ^ key) << 3) + (nn & 7)];
        }
        __bf16* dst = xt + ((size_t)(b * NN + n0 + nn)) * NC + c0 + cch;
        *(bf16x8*)(dst) = o[0];
        *(bf16x8*)(dst + 8) = o[1];
    }
}

// ---------- flash attention: 512 blocks (2/CU), 4 waves = 4-way j-split, 32 q-rows/block ----------
// Swapped QK^T (S^T = mfma(K,Q), 32x32x16): softmax lane-local, P built in-register
// (cvt_pk + permlane32_swap), no DS and no barriers in the main loop.
__global__ __launch_bounds__(256, 2) void flash_kernel(const __bf16* __restrict__ xt,
                                                       const __bf16* __restrict__ xv,
                                                       float* __restrict__ out) {
    __shared__ __align__(16) unsigned char smem[66560];  // 16KB sQ | reused as 64KB fbuf; +1KB sML
    __bf16* sQ = (__bf16*)smem;
    float* fb = (float*)smem;                            // epilogue only (sQ dead)
    float* sML = (float*)(smem + 65536);                 // [4][32][2]

    const int bid = blockIdx.x;
    const int xcd = bid & 7;
    const int b = xcd >> 1;                          // batch -> XCD pair; 4MB/batch = L2/XCD
    const int qblk = ((bid >> 3) << 1) | (xcd & 1);  // 0..127
    const int i_base = qblk * 32;

    const int tid = threadIdx.x;
    const int w = tid >> 6;        // wave 0..3 = j-group
    const int lane = tid & 63;
    const int li = lane & 31;      // q-index (n) / j-row (m) / c-row (m)
    const int hi = lane >> 5;      // k-half selector

    const __bf16* xtb = xt + (size_t)b * NN * NC;

    // ---- stage Q[i_base..+31][0..255] into LDS, XOR-swizzled (unit' = unit ^ row) ----
#pragma unroll
    for (int r4 = 0; r4 < 4; ++r4) {
        int d = r4 * 256 + w * 64 + lane;            // 16B-unit index, dest linear
        int row = d >> 5;
        int u = (d & 31) ^ (row & 31);               // pre-swizzled global source (rule #21)
        stage16(xtb + (size_t)(i_base + row) * NC + u * 8, sQ + (size_t)(r4 * 256 + w * 64) * 8);
    }
    __syncthreads();

    f32x16 acc[8];
#pragma unroll
    for (int ch = 0; ch < 8; ++ch) acc[ch] = (f32x16)0.f;
    float m_run = -3.0e38f, l_part = 0.f;

    const __bf16* kRow = xtb + (size_t)(w * 1024) * NC + li * NC + hi * 8;
    const __bf16* vRow = xv + ((size_t)(b * 128 + w * 32)) * (NC * BK) + li * BK + hi * 8;

    for (int t = 0; t < NT_W; ++t) {
        // ---- S^T = K Q^T : D[m=j][n=i], K-frags streamed from global (L1/L2) ----
        f32x16 s = (f32x16)0.f;
#pragma unroll
        for (int cstep = 0; cstep < 16; ++cstep) {
            bf16x8 kf = *(const bf16x8*)(kRow + cstep * 16);
            bf16x8 qf = *(const bf16x8*)(sQ + li * 256 + ((((cstep << 1) | hi) ^ li) << 3));
            s = __builtin_amdgcn_mfma_f32_32x32x16_bf16(kf, qf, s, 0, 0, 0);
        }

        // ---- lane-local online softmax (exact deferred max) ----
        float t0 = fmaxf(fmaxf(s[0], s[1]), fmaxf(s[2], s[3]));
        float t1 = fmaxf(fmaxf(s[4], s[5]), fmaxf(s[6], s[7]));
        float t2 = fmaxf(fmaxf(s[8], s[9]), fmaxf(s[10], s[11]));
        float t3 = fmaxf(fmaxf(s[12], s[13]), fmaxf(s[14], s[15]));
        float tmax = fmaxf(fmaxf(t0, t1), fmaxf(t2, t3));
        if (__any((int)(tmax > m_run))) {            // rare (~5 of 32 tiles)
            float om = __shfl_xor(tmax, 32);         // other half of the row
            float nm = fmaxf(m_run, fmaxf(tmax, om));
            float sc = __expf(m_run - nm);
            m_run = nm;
            l_part *= sc;
#pragma unroll
            for (int ch = 0; ch < 8; ++ch)
#pragma unroll
                for (int r = 0; r < 16; ++r) acc[ch][r] *= sc;
        }
        float p[16];
#pragma unroll
        for (int r = 0; r < 16; ++r) p[r] = __expf(s[r] - m_run);
        l_part += (((p[0] + p[1]) + (p[2] + p[3])) + ((p[4] + p[5]) + (p[6] + p[7]))) +
                  (((p[8] + p[9]) + (p[10] + p[11])) + ((p[12] + p[13]) + (p[14] + p[15])));

        // ---- P^T -> PV B-operands in-register (T12): 8 cvt_pk + 4 permlane32_swap ----
        int a0 = cvtpk(p[0], p[1]),   b0 = cvtpk(p[4], p[5]);
        int a1 = cvtpk(p[2], p[3]),   b1 = cvtpk(p[6], p[7]);
        int a2 = cvtpk(p[8], p[9]),   b2 = cvtpk(p[12], p[13]);
        int a3 = cvtpk(p[10], p[11]), b3 = cvtpk(p[14], p[15]);
        plswap(a0, b0);   // -> B0.vr0, B0.vr2
        plswap(a1, b1);   // -> B0.vr1, B0.vr3
        plswap(a2, b2);   // -> B1.vr0, B1.vr2
        plswap(a3, b3);   // -> B1.vr1, B1.vr3
        bf16x8 B0 = __builtin_bit_cast(bf16x8, (int4v){a0, a1, b0, b1});  // j 0..15
        bf16x8 B1 = __builtin_bit_cast(bf16x8, (int4v){a2, a3, b2, b3});  // j 16..31

        // ---- O^T += V^T P^T : D[m=c][n=i], V-frags from tile-major xv ----
#pragma unroll
        for (int ch = 0; ch < 8; ++ch) {
            const __bf16* vp = vRow + ch * 1024;
            bf16x8 v0 = *(const bf16x8*)(vp);
            bf16x8 v1 = *(const bf16x8*)(vp + 16);
            acc[ch] = __builtin_amdgcn_mfma_f32_32x32x16_bf16(v0, B0, acc[ch], 0, 0, 0);
            acc[ch] = __builtin_amdgcn_mfma_f32_32x32x16_bf16(v1, B1, acc[ch], 0, 0, 0);
        }

        kRow += BK * NC;     // next j-tile
        vRow += NC * BK;
    }

    // ---- merge the 4 j-split waves ----
    float l_full = l_part + __shfl_xor(l_part, 32);
    if (lane < 32) {
        sML[(w * 32 + li) * 2 + 0] = m_run;
        sML[(w * 32 + li) * 2 + 1] = l_full;
    }
    __syncthreads();                                  // sML ready; sQ dead
    float mw[4], lw[4];
#pragma unroll
    for (int k = 0; k < 4; ++k) {
        mw[k] = sML[(k * 32 + li) * 2 + 0];
        lw[k] = sML[(k * 32 + li) * 2 + 1];
    }
    float ms = fmaxf(fmaxf(mw[0], mw[1]), fmaxf(mw[2], mw[3]));
    float lsum = 0.f;
#pragma unroll
    for (int k = 0; k < 4; ++k) lsum += lw[k] * __expf(mw[k] - ms);
    const float inv = 1.f / lsum;
    const float f_own = __expf(m_run - ms);
#pragma unroll
    for (int ch = 0; ch < 8; ++ch)
#pragma unroll
        for (int r = 0; r < 16; ++r) acc[ch][r] *= f_own;

    if (w >= 2) {
        float* dst = fb + (size_t)(w - 2) * 8192;
#pragma unroll
        for (int ch = 0; ch < 8; ++ch)
#pragma unroll
            for (int r = 0; r < 16; ++r) dst[(ch * 16 + r) * 64 + lane] = acc[ch][r];
    }
    __syncthreads();
    if (w < 2) {
        const float* srcf = fb + (size_t)w * 8192;
#pragma unroll
        for (int ch = 0; ch < 8; ++ch)
#pragma unroll
            for (int r = 0; r < 16; ++r) acc[ch][r] += srcf[(ch * 16 + r) * 64 + lane];
    }
    __syncthreads();
    if (w == 1) {
#pragma unroll
        for (int ch = 0; ch < 8; ++ch)
#pragma unroll
            for (int r = 0; r < 16; ++r) fb[(ch * 16 + r) * 64 + lane] = acc[ch][r];
    }
    __syncthreads();
    if (w == 0) {
#pragma unroll
        for (int ch = 0; ch < 8; ++ch)
#pragma unroll
            for (int r = 0; r < 16; ++r) {
                float o = (acc[ch][r] + fb[(ch * 16 + r) * 64 + lane]) * inv;
                int c = ch * 32 + (r & 3) + ((r >> 2) << 3) + (hi << 2);
                out[((size_t)(b * NC + c)) * NN + i_base + li] = o;  // coalesced along n
            }
    }
}

extern "C" void kernel_launch(void* const* d_in, const int* in_sizes, int n_in,
                              void* d_out, int out_size, void* d_ws, size_t ws_size,
                              hipStream_t stream) {
    const float* x = (const float*)d_in[0];
    float* out = (float*)d_out;
    __bf16* xt = (__bf16*)d_ws;                       // [4][4096][256] bf16 = 8 MiB
    __bf16* xv = xt + (size_t)NB * NN * NC;           // [4][128][256][32] bf16 = 8 MiB

    prep_kernel<<<dim3(NN / 64, NC / 64, NB), dim3(256), 0, stream>>>(x, xt, xv);
    flash_kernel<<<dim3(512), dim3(256), 0, stream>>>(xt, xv, out);
}